// Round 7
// baseline (16124.434 us; speedup 1.0000x reference)
//
#include <hip/hip_runtime.h>
#include <hip/hip_bf16.h>
#include <stdint.h>

#define B_ 4096
#define D_ 64
#define T_ 8
#define H_ 128
#define K_ 32
#define NC_ 10
#define M_ 14

#define P_OFF (B_*NC_*T_)            /* 327680 */
#define N_OFF (P_OFF + B_*T_)        /* 360448 */
#define SX_OFF (N_OFF + B_*T_)       /* 393216 */

#define ROWS 8       /* batch rows per block */
#define THREADS 512
#define WREG 96      /* Whh weights held in VGPRs per row-thread (tail 32 via L1) */

// ---------------- Threefry-2x32 (20 rounds), exactly JAX's ----------------
__device__ __forceinline__ void tf2x32(uint32_t k0, uint32_t k1,
                                       uint32_t c0, uint32_t c1,
                                       uint32_t& o0, uint32_t& o1) {
  uint32_t ks2 = k0 ^ k1 ^ 0x1BD11BDAu;
  uint32_t x0 = c0 + k0, x1 = c1 + k1;
#define TF_R(r) { x0 += x1; x1 = ((x1 << (r)) | (x1 >> (32 - (r)))); x1 ^= x0; }
  TF_R(13) TF_R(15) TF_R(26) TF_R(6)
  x0 += k1; x1 += ks2 + 1u;
  TF_R(17) TF_R(29) TF_R(16) TF_R(24)
  x0 += ks2; x1 += k0 + 2u;
  TF_R(13) TF_R(15) TF_R(26) TF_R(6)
  x0 += k0; x1 += k1 + 3u;
  TF_R(17) TF_R(29) TF_R(16) TF_R(24)
  x0 += k1; x1 += ks2 + 4u;
  TF_R(13) TF_R(15) TF_R(26) TF_R(6)
  x0 += ks2; x1 += k0 + 5u;
#undef TF_R
  o0 = x0; o1 = x1;
}

// XLA ErfInv32 (Giles single-precision polynomial)
__device__ __forceinline__ float erfinv_f(float x) {
  float w = -log1pf(-x * x);
  float p;
  if (w < 5.0f) {
    w -= 2.5f;
    p = 2.81022636e-08f;
    p = fmaf(p, w, 3.43273939e-07f);
    p = fmaf(p, w, -3.5233877e-06f);
    p = fmaf(p, w, -4.39150654e-06f);
    p = fmaf(p, w, 0.00021858087f);
    p = fmaf(p, w, -0.00125372503f);
    p = fmaf(p, w, -0.00417768164f);
    p = fmaf(p, w, 0.246640727f);
    p = fmaf(p, w, 1.50140941f);
  } else {
    w = sqrtf(w) - 3.0f;
    p = -0.000200214257f;
    p = fmaf(p, w, 0.000100950558f);
    p = fmaf(p, w, 0.00134934322f);
    p = fmaf(p, w, -0.00367342844f);
    p = fmaf(p, w, 0.00573950773f);
    p = fmaf(p, w, -0.0076224613f);
    p = fmaf(p, w, 0.00943887047f);
    p = fmaf(p, w, 1.00167406f);
    p = fmaf(p, w, 2.83297682f);
  }
  return p * x;
}

__device__ __forceinline__ float sigmoid_f(float x) { return 1.0f / (1.0f + expf(-x)); }
__device__ __forceinline__ float softplus_f(float x) {
  return (x > 0.0f) ? (x + log1pf(expf(-x))) : log1pf(expf(x));
}

// 512 blocks x 512 threads, 8 batch rows/block.
// P1: threads 0..383 own one Whh row (96 w in VGPR + 32-float tail via L1),
//     compute 8 k-sequential chains (one per batch row) -> sh_gh.
//     Combine: 1024 (i,r) tasks / 512 threads apply exact GRU gate algebra.
// P2/P3/P4: round-6 mapping (idx = tid>>3, r = tid&7) unchanged.
__launch_bounds__(THREADS, 4)
__global__ void vrnn_kernel(const float* __restrict__ x, const float* __restrict__ sx,
                            const float* __restrict__ Wih, const float* __restrict__ Whh,
                            const float* __restrict__ bih, const float* __restrict__ bhh,
                            const float* __restrict__ We, const float* __restrict__ be,
                            const float* __restrict__ Wl, const float* __restrict__ bl,
                            const float* __restrict__ Wo, const float* __restrict__ bo,
                            const float* __restrict__ Whalt, const float* __restrict__ bhalt,
                            float* __restrict__ out) {
  __shared__ float sh_hA[ROWS][132];     // h carry / hb  (P1,P4 read; P3,step write)
  __shared__ float sh_hB[ROWS][132];     // h_gru         (combine write; P2 read)
  __shared__ float sh_gh[384 * 9];       // 13.8 KB  [row j][r] = j*9+r
  __shared__ float sh_gi[384 * 9];       // 13.8 KB
  __shared__ float sh_z[ROWS][36];
  __shared__ float sh_x[ROWS][68];
  __shared__ uint32_t sh_keys[T_ * M_][2];

  const int tid = threadIdx.x;
  const int r = tid & (ROWS - 1);
  const int idx = tid >> 3;              // 0..63
  const int i0 = idx * 2;                // P3/st: 2 hidden neurons
  const int kd = idx >> 1;               // P2 latent neuron
  const int role = idx & 1;              // 0: mu, 1: sigma
  const int c = idx >> 2;                // y dot index (0..15)
  const int q = idx & 3;                 // y quarter
  const int b = (int)blockIdx.x * ROWS + r;
  const bool isrow = (tid < 384);        // Whh/Wih row owner

  if (tid < T_ * M_) {
    uint32_t o0, o1;
    tf2x32(0u, 42u, 0u, (uint32_t)tid, o0, o1);
    sh_keys[tid][0] = o0;
    sh_keys[tid][1] = o1;
  }

  // ---- one-time: own Whh row k<96 into VGPRs; bias regs ----
  float w[WREG];
  float bhh_j = 0.0f, bih_j = 0.0f;
  const float* wrow = Whh + tid * H_;
  const float* wih_row = Wih + tid * D_;
  if (isrow) {
    bhh_j = bhh[tid];
    bih_j = bih[tid];
#pragma unroll
    for (int kk = 0; kk < WREG / 4; ++kk) {
      float4 t = *(const float4*)(wrow + kk * 4);
      w[kk * 4 + 0] = t.x; w[kk * 4 + 1] = t.y;
      w[kk * 4 + 2] = t.z; w[kk * 4 + 3] = t.w;
    }
  }

  // init h carry = sx (coalesced)
#pragma unroll
  for (int e = tid; e < ROWS * H_; e += THREADS)
    sh_hA[e >> 7][e & 127] = sx[(int)blockIdx.x * ROWS * H_ + e];
  __syncthreads();

#pragma unroll 1
  for (int t = 0; t < T_; ++t) {
    // ---- stage x_t ----
    {
      int row = tid >> 6, d = tid & 63;
      sh_x[row][d] = x[((int)blockIdx.x * ROWS + row) * (D_ * T_) + d * T_ + t];
    }
    __syncthreads();

    // ---- per-step gi: row-threads, 8 k-sequential chains -> sh_gi ----
    if (isrow) {
#pragma unroll 1
      for (int rr = 0; rr < ROWS; ++rr) {
        float acc = bih_j;
#pragma unroll
        for (int kk = 0; kk < D_ / 4; ++kk) {
          float4 xv = *(const float4*)&sh_x[rr][kk * 4];
          float4 wv = *(const float4*)(wih_row + kk * 4);
          acc = fmaf(wv.x, xv.x, acc);
          acc = fmaf(wv.y, xv.y, acc);
          acc = fmaf(wv.z, xv.z, acc);
          acc = fmaf(wv.w, xv.w, acc);
        }
        sh_gi[tid * 9 + rr] = acc;
      }
    }

    float st[2] = {0.0f, 0.0f};
    float yt = 0.0f;
    float csum = 0.0f, pmprev = 0.0f, rt = 0.0f;
    int nt = -1;
    __syncthreads();   // gi ready (also x-stage settled)

#pragma unroll 1
    for (int m = 0; m < M_; ++m) {
      // ---- P1-dot: row-threads, gh = Whh_row . h  (k = 0..127 sequential) ----
      if (isrow) {
#pragma unroll 1
        for (int rr = 0; rr < ROWS; ++rr) {
          float acc = bhh_j;
#pragma unroll
          for (int kk = 0; kk < WREG / 4; ++kk) {
            float4 hv = *(const float4*)&sh_hA[rr][kk * 4];
            acc = fmaf(w[kk * 4 + 0], hv.x, acc);
            acc = fmaf(w[kk * 4 + 1], hv.y, acc);
            acc = fmaf(w[kk * 4 + 2], hv.z, acc);
            acc = fmaf(w[kk * 4 + 3], hv.w, acc);
          }
#pragma unroll
          for (int kk = WREG / 4; kk < H_ / 4; ++kk) {
            float4 hv = *(const float4*)&sh_hA[rr][kk * 4];
            float4 wt = *(const float4*)(wrow + kk * 4);   // L1-resident tail
            acc = fmaf(wt.x, hv.x, acc);
            acc = fmaf(wt.y, hv.y, acc);
            acc = fmaf(wt.z, hv.z, acc);
            acc = fmaf(wt.w, hv.w, acc);
          }
          sh_gh[tid * 9 + rr] = acc;
        }
      }
      __syncthreads();

      // ---- combine: (i,r) tasks, exact GRU gate algebra -> sh_hB ----
#pragma unroll
      for (int vv = 0; vv < 2; ++vv) {
        int v = tid + vv * THREADS;
        int rr = v & 7, i = v >> 3;
        float ghr = sh_gh[(0 * H_ + i) * 9 + rr];
        float ghz = sh_gh[(1 * H_ + i) * 9 + rr];
        float ghn = sh_gh[(2 * H_ + i) * 9 + rr];
        float gir = sh_gi[(0 * H_ + i) * 9 + rr];
        float giz = sh_gi[(1 * H_ + i) * 9 + rr];
        float gin = sh_gi[(2 * H_ + i) * 9 + rr];
        float rg = sigmoid_f(gir + ghr);
        float zg = sigmoid_f(giz + ghz);
        float ng = tanhf(fmaf(rg, ghn, gin));
        float hprev = sh_hA[rr][i];
        sh_hB[rr][i] = (1.0f - zg) * ng + zg * hprev;
      }
      __syncthreads();

      // ---- P2: latent dot (mu or sigma chain), pair-combine, z draw ----
      {
        int wrowE = role ? (K_ + kd) : kd;
        float acc = be[wrowE];
        const float* wm = We + wrowE * H_;
#pragma unroll 2
        for (int kk = 0; kk < H_ / 4; ++kk) {
          float4 hv = *(const float4*)&sh_hB[r][kk * 4];
          float4 wv = *(const float4*)(wm + kk * 4);
          acc = fmaf(wv.x, hv.x, acc);
          acc = fmaf(wv.y, hv.y, acc);
          acc = fmaf(wv.z, hv.z, acc);
          acc = fmaf(wv.w, hv.w, acc);
        }
        float accP = __shfl_xor(acc, 8);   // partner (idx^1)
        if (role == 0) {
          float accM = acc, accS = accP;
          float sg = softplus_f(accS - 5.0f);
          uint32_t key0 = sh_keys[t * M_ + m][0];
          uint32_t key1 = sh_keys[t * M_ + m][1];
          uint32_t e = (uint32_t)b * 32u + (uint32_t)kd;
          uint32_t r0, r1;
          tf2x32(key0, key1, 0u, e, r0, r1);
          uint32_t bits = r0 ^ r1;
          float f = __uint_as_float((bits >> 9) | 0x3f800000u) - 1.0f;
          float u = fmaf(f, 2.0f, -0.99999994f);
          u = fmaxf(-0.99999994f, u);
          float eps = 1.41421356f * erfinv_f(u);
          sh_z[r][kd] = fmaf(eps, sg, accM);
        }
      }
      __syncthreads();

      // ---- P3: hb = tanh(z @ Wl.T + bl), z streamed from LDS -> sh_hA ----
      float hn[2];
#pragma unroll
      for (int ii = 0; ii < 2; ++ii) {
        int i = i0 + ii;
        float v = bl[i];
        const float* wl = Wl + i * K_;
#pragma unroll
        for (int kk = 0; kk < K_ / 4; ++kk) {
          float4 zv = *(const float4*)&sh_z[r][kk * 4];
          float4 wv = *(const float4*)(wl + kk * 4);
          v = fmaf(wv.x, zv.x, v);
          v = fmaf(wv.y, zv.y, v);
          v = fmaf(wv.z, zv.z, v);
          v = fmaf(wv.w, zv.w, v);
        }
        hn[ii] = tanhf(v);
        sh_hA[r][i] = hn[ii];
      }
      __syncthreads();

      // ---- P4: pn (full chain, all threads), y quarter + shuffle reduce ----
      {
        float pa = bhalt[0];
#pragma unroll 2
        for (int kk = 0; kk < H_ / 4; ++kk) {
          float4 hv = *(const float4*)&sh_hA[r][kk * 4];
          float4 av = *(const float4*)(Whalt + kk * 4);
          pa = fmaf(av.x, hv.x, pa); pa = fmaf(av.y, hv.y, pa);
          pa = fmaf(av.z, hv.z, pa); pa = fmaf(av.w, hv.w, pa);
        }
        float pn = sigmoid_f(pa);

        float yv = 0.0f;
        if (c < NC_) {
          float yq = (q == 0) ? bo[c] : 0.0f;
          const float* wo = Wo + c * H_ + q * 32;
#pragma unroll
          for (int kk = 0; kk < 8; ++kk) {
            float4 hv = *(const float4*)&sh_hA[r][q * 32 + kk * 4];
            float4 ov = *(const float4*)(wo + kk * 4);
            yq = fmaf(ov.x, hv.x, yq); yq = fmaf(ov.y, hv.y, yq);
            yq = fmaf(ov.z, hv.z, yq); yq = fmaf(ov.w, hv.w, yq);
          }
          yq += __shfl_xor(yq, 8);
          yq += __shfl_xor(yq, 16);
          yv = yq;
        }

        csum += pn;
        float pm = (m == M_ - 1) ? 1.0f : fminf(1.0f, csum);
        if (nt < 0 && (csum >= 1.0f || m == M_ - 1)) {
          nt = m;
          rt = (m == 0) ? 0.0f : (1.0f - pmprev);
        }
        float ph = pm - pmprev;
        pmprev = pm;
#pragma unroll
        for (int ii = 0; ii < 2; ++ii) st[ii] = fmaf(ph, hn[ii], st[ii]);
        yt = fmaf(ph, yv, yt);
      }
      // no barrier: next P1 reads hA (stable) and writes gh (last read 3 bars ago)
    }  // ticks

    // ---- step end: st becomes next h carry; write outputs ----
    __syncthreads();   // all P4 reads of hA complete before overwrite
#pragma unroll
    for (int ii = 0; ii < 2; ++ii) sh_hA[r][i0 + ii] = st[ii];
    if (c < NC_ && q == 0) out[b * (NC_ * T_) + c * T_ + t] = yt;
    if (idx == 40) {
      out[P_OFF + b * T_ + t] = (float)nt + rt;
      out[N_OFF + b * T_ + t] = (float)nt;
    }
    if (t == T_ - 1) {
#pragma unroll
      for (int ii = 0; ii < 2; ++ii)
        out[SX_OFF + b * H_ + i0 + ii] = st[ii];
    }
    __syncthreads();   // new carry + sh_x reuse safe before next step
  }  // steps
}

extern "C" void kernel_launch(void* const* d_in, const int* in_sizes, int n_in,
                              void* d_out, int out_size, void* d_ws, size_t ws_size,
                              hipStream_t stream) {
  (void)in_sizes; (void)n_in; (void)out_size; (void)d_ws; (void)ws_size;
  const float* x     = (const float*)d_in[0];
  const float* sx    = (const float*)d_in[1];
  const float* Wih   = (const float*)d_in[2];
  const float* Whh   = (const float*)d_in[3];
  const float* bih   = (const float*)d_in[4];
  const float* bhh   = (const float*)d_in[5];
  const float* We    = (const float*)d_in[6];
  const float* be    = (const float*)d_in[7];
  const float* Wl    = (const float*)d_in[8];
  const float* bl    = (const float*)d_in[9];
  const float* Wo    = (const float*)d_in[10];
  const float* bo    = (const float*)d_in[11];
  const float* Whalt = (const float*)d_in[12];
  const float* bhalt = (const float*)d_in[13];
  float* out = (float*)d_out;

  vrnn_kernel<<<dim3(B_ / ROWS), dim3(THREADS), 0, stream>>>(x, sx, Wih, Whh, bih, bhh,
                                                             We, be, Wl, bl, Wo, bo,
                                                             Whalt, bhalt, out);
}

// Round 8
// 12322.639 us; speedup vs baseline: 1.3085x; 1.3085x over previous
//
#include <hip/hip_runtime.h>
#include <hip/hip_bf16.h>
#include <stdint.h>

#define B_ 4096
#define D_ 64
#define T_ 8
#define H_ 128
#define K_ 32
#define NC_ 10
#define M_ 14

#define P_OFF (B_*NC_*T_)            /* 327680 */
#define N_OFF (P_OFF + B_*T_)        /* 360448 */
#define SX_OFF (N_OFF + B_*T_)       /* 393216 */

#define ROWS 8       /* batch rows per block */
#define THREADS 512
#define WREG 128     /* FULL Whh row in VGPRs per row-thread */

// ---------------- Threefry-2x32 (20 rounds), exactly JAX's ----------------
__device__ __forceinline__ void tf2x32(uint32_t k0, uint32_t k1,
                                       uint32_t c0, uint32_t c1,
                                       uint32_t& o0, uint32_t& o1) {
  uint32_t ks2 = k0 ^ k1 ^ 0x1BD11BDAu;
  uint32_t x0 = c0 + k0, x1 = c1 + k1;
#define TF_R(r) { x0 += x1; x1 = ((x1 << (r)) | (x1 >> (32 - (r)))); x1 ^= x0; }
  TF_R(13) TF_R(15) TF_R(26) TF_R(6)
  x0 += k1; x1 += ks2 + 1u;
  TF_R(17) TF_R(29) TF_R(16) TF_R(24)
  x0 += ks2; x1 += k0 + 2u;
  TF_R(13) TF_R(15) TF_R(26) TF_R(6)
  x0 += k0; x1 += k1 + 3u;
  TF_R(17) TF_R(29) TF_R(16) TF_R(24)
  x0 += k1; x1 += ks2 + 4u;
  TF_R(13) TF_R(15) TF_R(26) TF_R(6)
  x0 += ks2; x1 += k0 + 5u;
#undef TF_R
  o0 = x0; o1 = x1;
}

// XLA ErfInv32 (Giles single-precision polynomial)
__device__ __forceinline__ float erfinv_f(float x) {
  float w = -log1pf(-x * x);
  float p;
  if (w < 5.0f) {
    w -= 2.5f;
    p = 2.81022636e-08f;
    p = fmaf(p, w, 3.43273939e-07f);
    p = fmaf(p, w, -3.5233877e-06f);
    p = fmaf(p, w, -4.39150654e-06f);
    p = fmaf(p, w, 0.00021858087f);
    p = fmaf(p, w, -0.00125372503f);
    p = fmaf(p, w, -0.00417768164f);
    p = fmaf(p, w, 0.246640727f);
    p = fmaf(p, w, 1.50140941f);
  } else {
    w = sqrtf(w) - 3.0f;
    p = -0.000200214257f;
    p = fmaf(p, w, 0.000100950558f);
    p = fmaf(p, w, 0.00134934322f);
    p = fmaf(p, w, -0.00367342844f);
    p = fmaf(p, w, 0.00573950773f);
    p = fmaf(p, w, -0.0076224613f);
    p = fmaf(p, w, 0.00943887047f);
    p = fmaf(p, w, 1.00167406f);
    p = fmaf(p, w, 2.83297682f);
  }
  return p * x;
}

__device__ __forceinline__ float sigmoid_f(float x) { return 1.0f / (1.0f + expf(-x)); }
__device__ __forceinline__ float softplus_f(float x) {
  return (x > 0.0f) ? (x + log1pf(expf(-x))) : log1pf(expf(x));
}

// 512 blocks x 512 threads, 8 batch rows/block.
// P1: threads 0..383 own one FULL Whh row in VGPRs (128 regs),
//     compute 8 k-sequential chains (one per batch row) -> sh_gh.
//     h reads are wave-uniform LDS broadcasts (free).
//     Combine: 1024 (i,r) tasks / 512 threads apply exact GRU gate algebra.
// P2/P3/P4: round-6 mapping (idx = tid>>3, r = tid&7) unchanged.
// launch_bounds(512,2): VGPR cap 256 so w[128] really lives in registers.
__launch_bounds__(THREADS, 2)
__global__ void vrnn_kernel(const float* __restrict__ x, const float* __restrict__ sx,
                            const float* __restrict__ Wih, const float* __restrict__ Whh,
                            const float* __restrict__ bih, const float* __restrict__ bhh,
                            const float* __restrict__ We, const float* __restrict__ be,
                            const float* __restrict__ Wl, const float* __restrict__ bl,
                            const float* __restrict__ Wo, const float* __restrict__ bo,
                            const float* __restrict__ Whalt, const float* __restrict__ bhalt,
                            float* __restrict__ out) {
  __shared__ float sh_hA[ROWS][132];     // h carry / hb  (P1,P4 read; P3,step write)
  __shared__ float sh_hB[ROWS][132];     // h_gru         (combine write; P2 read)
  __shared__ float sh_gh[384 * 9];       // 13.8 KB  [row j][r] = j*9+r
  __shared__ float sh_gi[384 * 9];       // 13.8 KB
  __shared__ float sh_z[ROWS][36];
  __shared__ float sh_x[ROWS][68];
  __shared__ uint32_t sh_keys[T_ * M_][2];

  const int tid = threadIdx.x;
  const int r = tid & (ROWS - 1);
  const int idx = tid >> 3;              // 0..63
  const int i0 = idx * 2;                // P3/st: 2 hidden neurons
  const int kd = idx >> 1;               // P2 latent neuron
  const int role = idx & 1;              // 0: mu, 1: sigma
  const int c = idx >> 2;                // y dot index (0..15)
  const int q = idx & 3;                 // y quarter
  const int b = (int)blockIdx.x * ROWS + r;
  const bool isrow = (tid < 384);        // Whh/Wih row owner

  if (tid < T_ * M_) {
    uint32_t o0, o1;
    tf2x32(0u, 42u, 0u, (uint32_t)tid, o0, o1);
    sh_keys[tid][0] = o0;
    sh_keys[tid][1] = o1;
  }

  // ---- one-time: own FULL Whh row into VGPRs; bias regs ----
  float w[WREG];
  float bhh_j = 0.0f, bih_j = 0.0f;
  const float* wrow = Whh + tid * H_;
  const float* wih_row = Wih + tid * D_;
  if (isrow) {
    bhh_j = bhh[tid];
    bih_j = bih[tid];
#pragma unroll
    for (int kk = 0; kk < WREG / 4; ++kk) {
      float4 t = *(const float4*)(wrow + kk * 4);
      w[kk * 4 + 0] = t.x; w[kk * 4 + 1] = t.y;
      w[kk * 4 + 2] = t.z; w[kk * 4 + 3] = t.w;
    }
  }

  // init h carry = sx (coalesced)
#pragma unroll
  for (int e = tid; e < ROWS * H_; e += THREADS)
    sh_hA[e >> 7][e & 127] = sx[(int)blockIdx.x * ROWS * H_ + e];
  __syncthreads();

#pragma unroll 1
  for (int t = 0; t < T_; ++t) {
    // ---- stage x_t ----
    {
      int row = tid >> 6, d = tid & 63;
      sh_x[row][d] = x[((int)blockIdx.x * ROWS + row) * (D_ * T_) + d * T_ + t];
    }
    __syncthreads();

    // ---- per-step gi: row-threads, 8 k-sequential chains -> sh_gi ----
    if (isrow) {
#pragma unroll 1
      for (int rr = 0; rr < ROWS; ++rr) {
        float acc = bih_j;
#pragma unroll
        for (int kk = 0; kk < D_ / 4; ++kk) {
          float4 xv = *(const float4*)&sh_x[rr][kk * 4];
          float4 wv = *(const float4*)(wih_row + kk * 4);
          acc = fmaf(wv.x, xv.x, acc);
          acc = fmaf(wv.y, xv.y, acc);
          acc = fmaf(wv.z, xv.z, acc);
          acc = fmaf(wv.w, xv.w, acc);
        }
        sh_gi[tid * 9 + rr] = acc;
      }
    }

    float st[2] = {0.0f, 0.0f};
    float yt = 0.0f;
    float csum = 0.0f, pmprev = 0.0f, rt = 0.0f;
    int nt = -1;
    __syncthreads();   // gi ready (also x-stage settled)

#pragma unroll 1
    for (int m = 0; m < M_; ++m) {
      // ---- P1-dot: row-threads, gh = Whh_row . h, all from VGPRs + LDS bcast ----
      if (isrow) {
#pragma unroll 1
        for (int rr = 0; rr < ROWS; ++rr) {
          float acc = bhh_j;
#pragma unroll
          for (int kk = 0; kk < H_ / 4; ++kk) {
            float4 hv = *(const float4*)&sh_hA[rr][kk * 4];
            acc = fmaf(w[kk * 4 + 0], hv.x, acc);
            acc = fmaf(w[kk * 4 + 1], hv.y, acc);
            acc = fmaf(w[kk * 4 + 2], hv.z, acc);
            acc = fmaf(w[kk * 4 + 3], hv.w, acc);
          }
          sh_gh[tid * 9 + rr] = acc;
        }
      }
      __syncthreads();

      // ---- combine: (i,r) tasks, exact GRU gate algebra -> sh_hB ----
#pragma unroll
      for (int vv = 0; vv < 2; ++vv) {
        int v = tid + vv * THREADS;
        int rr = v & 7, i = v >> 3;
        float ghr = sh_gh[(0 * H_ + i) * 9 + rr];
        float ghz = sh_gh[(1 * H_ + i) * 9 + rr];
        float ghn = sh_gh[(2 * H_ + i) * 9 + rr];
        float gir = sh_gi[(0 * H_ + i) * 9 + rr];
        float giz = sh_gi[(1 * H_ + i) * 9 + rr];
        float gin = sh_gi[(2 * H_ + i) * 9 + rr];
        float rg = sigmoid_f(gir + ghr);
        float zg = sigmoid_f(giz + ghz);
        float ng = tanhf(fmaf(rg, ghn, gin));
        float hprev = sh_hA[rr][i];
        sh_hB[rr][i] = (1.0f - zg) * ng + zg * hprev;
      }
      __syncthreads();

      // ---- P2: latent dot (mu or sigma chain), pair-combine, z draw ----
      {
        int wrowE = role ? (K_ + kd) : kd;
        float acc = be[wrowE];
        const float* wm = We + wrowE * H_;
#pragma unroll 2
        for (int kk = 0; kk < H_ / 4; ++kk) {
          float4 hv = *(const float4*)&sh_hB[r][kk * 4];
          float4 wv = *(const float4*)(wm + kk * 4);
          acc = fmaf(wv.x, hv.x, acc);
          acc = fmaf(wv.y, hv.y, acc);
          acc = fmaf(wv.z, hv.z, acc);
          acc = fmaf(wv.w, hv.w, acc);
        }
        float accP = __shfl_xor(acc, 8);   // partner (idx^1)
        if (role == 0) {
          float accM = acc, accS = accP;
          float sg = softplus_f(accS - 5.0f);
          uint32_t key0 = sh_keys[t * M_ + m][0];
          uint32_t key1 = sh_keys[t * M_ + m][1];
          uint32_t e = (uint32_t)b * 32u + (uint32_t)kd;
          uint32_t r0, r1;
          tf2x32(key0, key1, 0u, e, r0, r1);
          uint32_t bits = r0 ^ r1;
          float f = __uint_as_float((bits >> 9) | 0x3f800000u) - 1.0f;
          float u = fmaf(f, 2.0f, -0.99999994f);
          u = fmaxf(-0.99999994f, u);
          float eps = 1.41421356f * erfinv_f(u);
          sh_z[r][kd] = fmaf(eps, sg, accM);
        }
      }
      __syncthreads();

      // ---- P3: hb = tanh(z @ Wl.T + bl), z streamed from LDS -> sh_hA ----
      float hn[2];
#pragma unroll
      for (int ii = 0; ii < 2; ++ii) {
        int i = i0 + ii;
        float v = bl[i];
        const float* wl = Wl + i * K_;
#pragma unroll
        for (int kk = 0; kk < K_ / 4; ++kk) {
          float4 zv = *(const float4*)&sh_z[r][kk * 4];
          float4 wv = *(const float4*)(wl + kk * 4);
          v = fmaf(wv.x, zv.x, v);
          v = fmaf(wv.y, zv.y, v);
          v = fmaf(wv.z, zv.z, v);
          v = fmaf(wv.w, zv.w, v);
        }
        hn[ii] = tanhf(v);
        sh_hA[r][i] = hn[ii];
      }
      __syncthreads();

      // ---- P4: pn (full chain, all threads), y quarter + shuffle reduce ----
      {
        float pa = bhalt[0];
#pragma unroll 2
        for (int kk = 0; kk < H_ / 4; ++kk) {
          float4 hv = *(const float4*)&sh_hA[r][kk * 4];
          float4 av = *(const float4*)(Whalt + kk * 4);
          pa = fmaf(av.x, hv.x, pa); pa = fmaf(av.y, hv.y, pa);
          pa = fmaf(av.z, hv.z, pa); pa = fmaf(av.w, hv.w, pa);
        }
        float pn = sigmoid_f(pa);

        float yv = 0.0f;
        if (c < NC_) {
          float yq = (q == 0) ? bo[c] : 0.0f;
          const float* wo = Wo + c * H_ + q * 32;
#pragma unroll
          for (int kk = 0; kk < 8; ++kk) {
            float4 hv = *(const float4*)&sh_hA[r][q * 32 + kk * 4];
            float4 ov = *(const float4*)(wo + kk * 4);
            yq = fmaf(ov.x, hv.x, yq); yq = fmaf(ov.y, hv.y, yq);
            yq = fmaf(ov.z, hv.z, yq); yq = fmaf(ov.w, hv.w, yq);
          }
          yq += __shfl_xor(yq, 8);
          yq += __shfl_xor(yq, 16);
          yv = yq;
        }

        csum += pn;
        float pm = (m == M_ - 1) ? 1.0f : fminf(1.0f, csum);
        if (nt < 0 && (csum >= 1.0f || m == M_ - 1)) {
          nt = m;
          rt = (m == 0) ? 0.0f : (1.0f - pmprev);
        }
        float ph = pm - pmprev;
        pmprev = pm;
#pragma unroll
        for (int ii = 0; ii < 2; ++ii) st[ii] = fmaf(ph, hn[ii], st[ii]);
        yt = fmaf(ph, yv, yt);
      }
      // no barrier: next P1 reads hA (stable) and writes gh (last read 3 bars ago)
    }  // ticks

    // ---- step end: st becomes next h carry; write outputs ----
    __syncthreads();   // all P4 reads of hA complete before overwrite
#pragma unroll
    for (int ii = 0; ii < 2; ++ii) sh_hA[r][i0 + ii] = st[ii];
    if (c < NC_ && q == 0) out[b * (NC_ * T_) + c * T_ + t] = yt;
    if (idx == 40) {
      out[P_OFF + b * T_ + t] = (float)nt + rt;
      out[N_OFF + b * T_ + t] = (float)nt;
    }
    if (t == T_ - 1) {
#pragma unroll
      for (int ii = 0; ii < 2; ++ii)
        out[SX_OFF + b * H_ + i0 + ii] = st[ii];
    }
    __syncthreads();   // new carry + sh_x reuse safe before next step
  }  // steps
}

extern "C" void kernel_launch(void* const* d_in, const int* in_sizes, int n_in,
                              void* d_out, int out_size, void* d_ws, size_t ws_size,
                              hipStream_t stream) {
  (void)in_sizes; (void)n_in; (void)out_size; (void)d_ws; (void)ws_size;
  const float* x     = (const float*)d_in[0];
  const float* sx    = (const float*)d_in[1];
  const float* Wih   = (const float*)d_in[2];
  const float* Whh   = (const float*)d_in[3];
  const float* bih   = (const float*)d_in[4];
  const float* bhh   = (const float*)d_in[5];
  const float* We    = (const float*)d_in[6];
  const float* be    = (const float*)d_in[7];
  const float* Wl    = (const float*)d_in[8];
  const float* bl    = (const float*)d_in[9];
  const float* Wo    = (const float*)d_in[10];
  const float* bo    = (const float*)d_in[11];
  const float* Whalt = (const float*)d_in[12];
  const float* bhalt = (const float*)d_in[13];
  float* out = (float*)d_out;

  vrnn_kernel<<<dim3(B_ / ROWS), dim3(THREADS), 0, stream>>>(x, sx, Wih, Whh, bih, bhh,
                                                             We, be, Wl, bl, Wo, bo,
                                                             Whalt, bhalt, out);
}

// Round 9
// 11685.181 us; speedup vs baseline: 1.3799x; 1.0546x over previous
//
#include <hip/hip_runtime.h>
#include <hip/hip_bf16.h>
#include <stdint.h>

#define B_ 4096
#define D_ 64
#define T_ 8
#define H_ 128
#define K_ 32
#define NC_ 10
#define M_ 14

#define P_OFF (B_*NC_*T_)            /* 327680 */
#define N_OFF (P_OFF + B_*T_)        /* 360448 */
#define SX_OFF (N_OFF + B_*T_)       /* 393216 */

#define ROWS 8       /* batch rows per block */
#define THREADS 512
#define WREG 128     /* FULL Whh row in VGPRs per row-thread */

// ---------------- Threefry-2x32 (20 rounds), exactly JAX's ----------------
__device__ __forceinline__ void tf2x32(uint32_t k0, uint32_t k1,
                                       uint32_t c0, uint32_t c1,
                                       uint32_t& o0, uint32_t& o1) {
  uint32_t ks2 = k0 ^ k1 ^ 0x1BD11BDAu;
  uint32_t x0 = c0 + k0, x1 = c1 + k1;
#define TF_R(r) { x0 += x1; x1 = ((x1 << (r)) | (x1 >> (32 - (r)))); x1 ^= x0; }
  TF_R(13) TF_R(15) TF_R(26) TF_R(6)
  x0 += k1; x1 += ks2 + 1u;
  TF_R(17) TF_R(29) TF_R(16) TF_R(24)
  x0 += ks2; x1 += k0 + 2u;
  TF_R(13) TF_R(15) TF_R(26) TF_R(6)
  x0 += k0; x1 += k1 + 3u;
  TF_R(17) TF_R(29) TF_R(16) TF_R(24)
  x0 += k1; x1 += ks2 + 4u;
  TF_R(13) TF_R(15) TF_R(26) TF_R(6)
  x0 += ks2; x1 += k0 + 5u;
#undef TF_R
  o0 = x0; o1 = x1;
}

// XLA ErfInv32 (Giles single-precision polynomial)
__device__ __forceinline__ float erfinv_f(float x) {
  float w = -log1pf(-x * x);
  float p;
  if (w < 5.0f) {
    w -= 2.5f;
    p = 2.81022636e-08f;
    p = fmaf(p, w, 3.43273939e-07f);
    p = fmaf(p, w, -3.5233877e-06f);
    p = fmaf(p, w, -4.39150654e-06f);
    p = fmaf(p, w, 0.00021858087f);
    p = fmaf(p, w, -0.00125372503f);
    p = fmaf(p, w, -0.00417768164f);
    p = fmaf(p, w, 0.246640727f);
    p = fmaf(p, w, 1.50140941f);
  } else {
    w = sqrtf(w) - 3.0f;
    p = -0.000200214257f;
    p = fmaf(p, w, 0.000100950558f);
    p = fmaf(p, w, 0.00134934322f);
    p = fmaf(p, w, -0.00367342844f);
    p = fmaf(p, w, 0.00573950773f);
    p = fmaf(p, w, -0.0076224613f);
    p = fmaf(p, w, 0.00943887047f);
    p = fmaf(p, w, 1.00167406f);
    p = fmaf(p, w, 2.83297682f);
  }
  return p * x;
}

__device__ __forceinline__ float sigmoid_f(float x) { return 1.0f / (1.0f + expf(-x)); }
__device__ __forceinline__ float softplus_f(float x) {
  return (x > 0.0f) ? (x + log1pf(expf(-x))) : log1pf(expf(x));
}

// 512 blocks x 512 threads, 8 batch rows/block.
// P1: threads 0..383 own one FULL Whh row in VGPRs (128 regs),
//     compute 8 k-sequential chains (one per batch row) -> sh_gh.
//     h reads are wave-uniform LDS broadcasts (free).
//     Combine: 1024 (i,r) tasks / 512 threads apply exact GRU gate algebra.
// P2/P3/P4: round-6 mapping (idx = tid>>3, r = tid&7) unchanged.
// launch_bounds(512,1): hipcc's 2nd arg is min BLOCKS/CU (CUDA semantics).
//   arg=1 -> 8 waves/CU = 2 waves/SIMD -> VGPR cap 256, so w[128] fits.
//   (arg=2 capped at 128 VGPRs and spilled w[] -> 26 GB scratch reads, r8.)
__launch_bounds__(THREADS, 1)
__global__ void vrnn_kernel(const float* __restrict__ x, const float* __restrict__ sx,
                            const float* __restrict__ Wih, const float* __restrict__ Whh,
                            const float* __restrict__ bih, const float* __restrict__ bhh,
                            const float* __restrict__ We, const float* __restrict__ be,
                            const float* __restrict__ Wl, const float* __restrict__ bl,
                            const float* __restrict__ Wo, const float* __restrict__ bo,
                            const float* __restrict__ Whalt, const float* __restrict__ bhalt,
                            float* __restrict__ out) {
  __shared__ float sh_hA[ROWS][132];     // h carry / hb  (P1,P4 read; P3,step write)
  __shared__ float sh_hB[ROWS][132];     // h_gru         (combine write; P2 read)
  __shared__ float sh_gh[384 * 9];       // 13.8 KB  [row j][r] = j*9+r
  __shared__ float sh_gi[384 * 9];       // 13.8 KB
  __shared__ float sh_z[ROWS][36];
  __shared__ float sh_x[ROWS][68];
  __shared__ uint32_t sh_keys[T_ * M_][2];

  const int tid = threadIdx.x;
  const int r = tid & (ROWS - 1);
  const int idx = tid >> 3;              // 0..63
  const int i0 = idx * 2;                // P3/st: 2 hidden neurons
  const int kd = idx >> 1;               // P2 latent neuron
  const int role = idx & 1;              // 0: mu, 1: sigma
  const int c = idx >> 2;                // y dot index (0..15)
  const int q = idx & 3;                 // y quarter
  const int b = (int)blockIdx.x * ROWS + r;
  const bool isrow = (tid < 384);        // Whh/Wih row owner

  if (tid < T_ * M_) {
    uint32_t o0, o1;
    tf2x32(0u, 42u, 0u, (uint32_t)tid, o0, o1);
    sh_keys[tid][0] = o0;
    sh_keys[tid][1] = o1;
  }

  // ---- one-time: own FULL Whh row into VGPRs; bias regs ----
  float w[WREG];
  float bhh_j = 0.0f, bih_j = 0.0f;
  const float* wrow = Whh + tid * H_;
  const float* wih_row = Wih + tid * D_;
  if (isrow) {
    bhh_j = bhh[tid];
    bih_j = bih[tid];
#pragma unroll
    for (int kk = 0; kk < WREG / 4; ++kk) {
      float4 t = *(const float4*)(wrow + kk * 4);
      w[kk * 4 + 0] = t.x; w[kk * 4 + 1] = t.y;
      w[kk * 4 + 2] = t.z; w[kk * 4 + 3] = t.w;
    }
  }

  // init h carry = sx (coalesced)
#pragma unroll
  for (int e = tid; e < ROWS * H_; e += THREADS)
    sh_hA[e >> 7][e & 127] = sx[(int)blockIdx.x * ROWS * H_ + e];
  __syncthreads();

#pragma unroll 1
  for (int t = 0; t < T_; ++t) {
    // ---- stage x_t ----
    {
      int row = tid >> 6, d = tid & 63;
      sh_x[row][d] = x[((int)blockIdx.x * ROWS + row) * (D_ * T_) + d * T_ + t];
    }
    __syncthreads();

    // ---- per-step gi: row-threads, 8 k-sequential chains -> sh_gi ----
    if (isrow) {
#pragma unroll 1
      for (int rr = 0; rr < ROWS; ++rr) {
        float acc = bih_j;
#pragma unroll
        for (int kk = 0; kk < D_ / 4; ++kk) {
          float4 xv = *(const float4*)&sh_x[rr][kk * 4];
          float4 wv = *(const float4*)(wih_row + kk * 4);
          acc = fmaf(wv.x, xv.x, acc);
          acc = fmaf(wv.y, xv.y, acc);
          acc = fmaf(wv.z, xv.z, acc);
          acc = fmaf(wv.w, xv.w, acc);
        }
        sh_gi[tid * 9 + rr] = acc;
      }
    }

    float st[2] = {0.0f, 0.0f};
    float yt = 0.0f;
    float csum = 0.0f, pmprev = 0.0f, rt = 0.0f;
    int nt = -1;
    __syncthreads();   // gi ready (also x-stage settled)

#pragma unroll 1
    for (int m = 0; m < M_; ++m) {
      // ---- P1-dot: row-threads, gh = Whh_row . h, all from VGPRs + LDS bcast ----
      if (isrow) {
#pragma unroll 1
        for (int rr = 0; rr < ROWS; ++rr) {
          float acc = bhh_j;
#pragma unroll
          for (int kk = 0; kk < H_ / 4; ++kk) {
            float4 hv = *(const float4*)&sh_hA[rr][kk * 4];
            acc = fmaf(w[kk * 4 + 0], hv.x, acc);
            acc = fmaf(w[kk * 4 + 1], hv.y, acc);
            acc = fmaf(w[kk * 4 + 2], hv.z, acc);
            acc = fmaf(w[kk * 4 + 3], hv.w, acc);
          }
          sh_gh[tid * 9 + rr] = acc;
        }
      }
      __syncthreads();

      // ---- combine: (i,r) tasks, exact GRU gate algebra -> sh_hB ----
#pragma unroll
      for (int vv = 0; vv < 2; ++vv) {
        int v = tid + vv * THREADS;
        int rr = v & 7, i = v >> 3;
        float ghr = sh_gh[(0 * H_ + i) * 9 + rr];
        float ghz = sh_gh[(1 * H_ + i) * 9 + rr];
        float ghn = sh_gh[(2 * H_ + i) * 9 + rr];
        float gir = sh_gi[(0 * H_ + i) * 9 + rr];
        float giz = sh_gi[(1 * H_ + i) * 9 + rr];
        float gin = sh_gi[(2 * H_ + i) * 9 + rr];
        float rg = sigmoid_f(gir + ghr);
        float zg = sigmoid_f(giz + ghz);
        float ng = tanhf(fmaf(rg, ghn, gin));
        float hprev = sh_hA[rr][i];
        sh_hB[rr][i] = (1.0f - zg) * ng + zg * hprev;
      }
      __syncthreads();

      // ---- P2: latent dot (mu or sigma chain), pair-combine, z draw ----
      {
        int wrowE = role ? (K_ + kd) : kd;
        float acc = be[wrowE];
        const float* wm = We + wrowE * H_;
#pragma unroll 2
        for (int kk = 0; kk < H_ / 4; ++kk) {
          float4 hv = *(const float4*)&sh_hB[r][kk * 4];
          float4 wv = *(const float4*)(wm + kk * 4);
          acc = fmaf(wv.x, hv.x, acc);
          acc = fmaf(wv.y, hv.y, acc);
          acc = fmaf(wv.z, hv.z, acc);
          acc = fmaf(wv.w, hv.w, acc);
        }
        float accP = __shfl_xor(acc, 8);   // partner (idx^1)
        if (role == 0) {
          float accM = acc, accS = accP;
          float sg = softplus_f(accS - 5.0f);
          uint32_t key0 = sh_keys[t * M_ + m][0];
          uint32_t key1 = sh_keys[t * M_ + m][1];
          uint32_t e = (uint32_t)b * 32u + (uint32_t)kd;
          uint32_t r0, r1;
          tf2x32(key0, key1, 0u, e, r0, r1);
          uint32_t bits = r0 ^ r1;
          float f = __uint_as_float((bits >> 9) | 0x3f800000u) - 1.0f;
          float u = fmaf(f, 2.0f, -0.99999994f);
          u = fmaxf(-0.99999994f, u);
          float eps = 1.41421356f * erfinv_f(u);
          sh_z[r][kd] = fmaf(eps, sg, accM);
        }
      }
      __syncthreads();

      // ---- P3: hb = tanh(z @ Wl.T + bl), z streamed from LDS -> sh_hA ----
      float hn[2];
#pragma unroll
      for (int ii = 0; ii < 2; ++ii) {
        int i = i0 + ii;
        float v = bl[i];
        const float* wl = Wl + i * K_;
#pragma unroll
        for (int kk = 0; kk < K_ / 4; ++kk) {
          float4 zv = *(const float4*)&sh_z[r][kk * 4];
          float4 wv = *(const float4*)(wl + kk * 4);
          v = fmaf(wv.x, zv.x, v);
          v = fmaf(wv.y, zv.y, v);
          v = fmaf(wv.z, zv.z, v);
          v = fmaf(wv.w, zv.w, v);
        }
        hn[ii] = tanhf(v);
        sh_hA[r][i] = hn[ii];
      }
      __syncthreads();

      // ---- P4: pn (full chain, all threads), y quarter + shuffle reduce ----
      {
        float pa = bhalt[0];
#pragma unroll 2
        for (int kk = 0; kk < H_ / 4; ++kk) {
          float4 hv = *(const float4*)&sh_hA[r][kk * 4];
          float4 av = *(const float4*)(Whalt + kk * 4);
          pa = fmaf(av.x, hv.x, pa); pa = fmaf(av.y, hv.y, pa);
          pa = fmaf(av.z, hv.z, pa); pa = fmaf(av.w, hv.w, pa);
        }
        float pn = sigmoid_f(pa);

        float yv = 0.0f;
        if (c < NC_) {
          float yq = (q == 0) ? bo[c] : 0.0f;
          const float* wo = Wo + c * H_ + q * 32;
#pragma unroll
          for (int kk = 0; kk < 8; ++kk) {
            float4 hv = *(const float4*)&sh_hA[r][q * 32 + kk * 4];
            float4 ov = *(const float4*)(wo + kk * 4);
            yq = fmaf(ov.x, hv.x, yq); yq = fmaf(ov.y, hv.y, yq);
            yq = fmaf(ov.z, hv.z, yq); yq = fmaf(ov.w, hv.w, yq);
          }
          yq += __shfl_xor(yq, 8);
          yq += __shfl_xor(yq, 16);
          yv = yq;
        }

        csum += pn;
        float pm = (m == M_ - 1) ? 1.0f : fminf(1.0f, csum);
        if (nt < 0 && (csum >= 1.0f || m == M_ - 1)) {
          nt = m;
          rt = (m == 0) ? 0.0f : (1.0f - pmprev);
        }
        float ph = pm - pmprev;
        pmprev = pm;
#pragma unroll
        for (int ii = 0; ii < 2; ++ii) st[ii] = fmaf(ph, hn[ii], st[ii]);
        yt = fmaf(ph, yv, yt);
      }
      // no barrier: next P1 reads hA (stable) and writes gh (last read 3 bars ago)
    }  // ticks

    // ---- step end: st becomes next h carry; write outputs ----
    __syncthreads();   // all P4 reads of hA complete before overwrite
#pragma unroll
    for (int ii = 0; ii < 2; ++ii) sh_hA[r][i0 + ii] = st[ii];
    if (c < NC_ && q == 0) out[b * (NC_ * T_) + c * T_ + t] = yt;
    if (idx == 40) {
      out[P_OFF + b * T_ + t] = (float)nt + rt;
      out[N_OFF + b * T_ + t] = (float)nt;
    }
    if (t == T_ - 1) {
#pragma unroll
      for (int ii = 0; ii < 2; ++ii)
        out[SX_OFF + b * H_ + i0 + ii] = st[ii];
    }
    __syncthreads();   // new carry + sh_x reuse safe before next step
  }  // steps
}

extern "C" void kernel_launch(void* const* d_in, const int* in_sizes, int n_in,
                              void* d_out, int out_size, void* d_ws, size_t ws_size,
                              hipStream_t stream) {
  (void)in_sizes; (void)n_in; (void)out_size; (void)d_ws; (void)ws_size;
  const float* x     = (const float*)d_in[0];
  const float* sx    = (const float*)d_in[1];
  const float* Wih   = (const float*)d_in[2];
  const float* Whh   = (const float*)d_in[3];
  const float* bih   = (const float*)d_in[4];
  const float* bhh   = (const float*)d_in[5];
  const float* We    = (const float*)d_in[6];
  const float* be    = (const float*)d_in[7];
  const float* Wl    = (const float*)d_in[8];
  const float* bl    = (const float*)d_in[9];
  const float* Wo    = (const float*)d_in[10];
  const float* bo    = (const float*)d_in[11];
  const float* Whalt = (const float*)d_in[12];
  const float* bhalt = (const float*)d_in[13];
  float* out = (float*)d_out;

  vrnn_kernel<<<dim3(B_ / ROWS), dim3(THREADS), 0, stream>>>(x, sx, Wih, Whh, bih, bhh,
                                                             We, be, Wl, bl, Wo, bo,
                                                             Whalt, bhalt, out);
}

// Round 10
// 6390.496 us; speedup vs baseline: 2.5232x; 1.8285x over previous
//
#include <hip/hip_runtime.h>
#include <hip/hip_bf16.h>
#include <stdint.h>

#define B_ 4096
#define D_ 64
#define T_ 8
#define H_ 128
#define K_ 32
#define NC_ 10
#define M_ 14

#define P_OFF (B_*NC_*T_)            /* 327680 */
#define N_OFF (P_OFF + B_*T_)        /* 360448 */
#define SX_OFF (N_OFF + B_*T_)       /* 393216 */

#define ROWS 16      /* batch rows per block (1 block/CU) */
#define THREADS 1024

/* ws float offsets for transposed weights: W2[kk][row][4] layouts */
#define WS_WHH 0        /* 32 kk x 384 rows x4 = 49152 */
#define WS_WIH 49152    /* 16 kk x 384 x4 = 24576 */
#define WS_WE  73728    /* 32 kk x 64 x4  = 8192 */
#define WS_WL  81920    /* 8 kk x 128 x4  = 4096 */
#define WS_TOT 86016    /* 344 KB */

// ---------------- Threefry-2x32 (20 rounds), exactly JAX's ----------------
__device__ __forceinline__ void tf2x32(uint32_t k0, uint32_t k1,
                                       uint32_t c0, uint32_t c1,
                                       uint32_t& o0, uint32_t& o1) {
  uint32_t ks2 = k0 ^ k1 ^ 0x1BD11BDAu;
  uint32_t x0 = c0 + k0, x1 = c1 + k1;
#define TF_R(r) { x0 += x1; x1 = ((x1 << (r)) | (x1 >> (32 - (r)))); x1 ^= x0; }
  TF_R(13) TF_R(15) TF_R(26) TF_R(6)
  x0 += k1; x1 += ks2 + 1u;
  TF_R(17) TF_R(29) TF_R(16) TF_R(24)
  x0 += ks2; x1 += k0 + 2u;
  TF_R(13) TF_R(15) TF_R(26) TF_R(6)
  x0 += k0; x1 += k1 + 3u;
  TF_R(17) TF_R(29) TF_R(16) TF_R(24)
  x0 += k1; x1 += ks2 + 4u;
  TF_R(13) TF_R(15) TF_R(26) TF_R(6)
  x0 += ks2; x1 += k0 + 5u;
#undef TF_R
  o0 = x0; o1 = x1;
}

// XLA ErfInv32 (Giles single-precision polynomial)
__device__ __forceinline__ float erfinv_f(float x) {
  float w = -log1pf(-x * x);
  float p;
  if (w < 5.0f) {
    w -= 2.5f;
    p = 2.81022636e-08f;
    p = fmaf(p, w, 3.43273939e-07f);
    p = fmaf(p, w, -3.5233877e-06f);
    p = fmaf(p, w, -4.39150654e-06f);
    p = fmaf(p, w, 0.00021858087f);
    p = fmaf(p, w, -0.00125372503f);
    p = fmaf(p, w, -0.00417768164f);
    p = fmaf(p, w, 0.246640727f);
    p = fmaf(p, w, 1.50140941f);
  } else {
    w = sqrtf(w) - 3.0f;
    p = -0.000200214257f;
    p = fmaf(p, w, 0.000100950558f);
    p = fmaf(p, w, 0.00134934322f);
    p = fmaf(p, w, -0.00367342844f);
    p = fmaf(p, w, 0.00573950773f);
    p = fmaf(p, w, -0.0076224613f);
    p = fmaf(p, w, 0.00943887047f);
    p = fmaf(p, w, 1.00167406f);
    p = fmaf(p, w, 2.83297682f);
  }
  return p * x;
}

__device__ __forceinline__ float sigmoid_f(float x) { return 1.0f / (1.0f + expf(-x)); }
__device__ __forceinline__ float softplus_f(float x) {
  return (x > 0.0f) ? (x + log1pf(expf(-x))) : log1pf(expf(x));
}

// ---- prologue: transpose weights into ws as W2[kk][row][4] (coalesced reads) ----
__launch_bounds__(256)
__global__ void reorder_kernel(const float* __restrict__ Whh, const float* __restrict__ Wih,
                               const float* __restrict__ We, const float* __restrict__ Wl,
                               float* __restrict__ ws) {
  int i = (int)blockIdx.x * 256 + (int)threadIdx.x;
  if (i < 49152) {                       // Whh: 384x128
    int e = i & 3, ch = i >> 2, j = ch % 384, kk = ch / 384;
    ws[WS_WHH + i] = Whh[j * H_ + kk * 4 + e];
  } else if (i < 73728) {                // Wih: 384x64
    int x2 = i - WS_WIH;
    int e = x2 & 3, ch = x2 >> 2, j = ch % 384, kk = ch / 384;
    ws[i] = Wih[j * D_ + kk * 4 + e];
  } else if (i < 81920) {                // We: 64x128
    int x2 = i - WS_WE;
    int e = x2 & 3, ch = x2 >> 2, j = ch % 64, kk = ch / 64;
    ws[i] = We[j * H_ + kk * 4 + e];
  } else if (i < WS_TOT) {               // Wl: 128x32
    int x2 = i - WS_WL;
    int e = x2 & 3, ch = x2 >> 2, j = ch % 128, kk = ch / 128;
    ws[i] = Wl[j * K_ + kk * 4 + e];
  }
}

// 256 blocks x 1024 threads, 16 batch rows/block (one pass over B).
// P1/gi: threads 0..383 own matrix row j=tid; coalesced W2 loads, each chunk
//        reused for 16 batch rows via LDS-broadcast h reads. Chains k-ascending.
// combine: 2048 (i,r) tasks, exact GRU algebra.
// P2: 256 th = (We-row 0..63) x (row-quad 0..3), chains intact. zdraw: 512 th.
// P3: 256 th = (Wl-row 0..127) x (row-half 0..1). P4: round-6 logic, r=tid&15.
__launch_bounds__(THREADS, 1)
__global__ void vrnn_kernel(const float* __restrict__ x, const float* __restrict__ sx,
                            const float* __restrict__ bih, const float* __restrict__ bhh,
                            const float* __restrict__ be, const float* __restrict__ bl,
                            const float* __restrict__ Wo, const float* __restrict__ bo,
                            const float* __restrict__ Whalt, const float* __restrict__ bhalt,
                            const float* __restrict__ ws, float* __restrict__ out) {
  __shared__ float sh_hA[ROWS][132];     // h carry / hb
  __shared__ float sh_hB[ROWS][132];     // h_gru
  __shared__ float sh_gh[384 * 17];      // 26.1 KB
  __shared__ float sh_gi[384 * 17];      // 26.1 KB
  __shared__ float sh_enc[64 * 17];      // 4.4 KB
  __shared__ float sh_z[ROWS][36];
  __shared__ float sh_x[ROWS][68];
  __shared__ uint32_t sh_keys[T_ * M_][2];

  const int tid = (int)threadIdx.x;
  const int r16 = tid & 15;
  const int idx = tid >> 4;              // 0..63
  const int i0 = idx * 2;
  const int c = idx >> 2;                // y dot (0..15)
  const int q = idx & 3;                 // y quarter
  const int blk = (int)blockIdx.x;
  const int b = blk * ROWS + r16;
  const bool isrow = (tid < 384);

  const float* whh2 = ws + WS_WHH;
  const float* wih2 = ws + WS_WIH;
  const float* we2  = ws + WS_WE;
  const float* wl2  = ws + WS_WL;

  if (tid < T_ * M_) {
    uint32_t o0, o1;
    tf2x32(0u, 42u, 0u, (uint32_t)tid, o0, o1);
    sh_keys[tid][0] = o0;
    sh_keys[tid][1] = o1;
  }

  float bhh_j = 0.0f, bih_j = 0.0f;
  if (isrow) { bhh_j = bhh[tid]; bih_j = bih[tid]; }

  // init h carry = sx
#pragma unroll
  for (int e = tid; e < ROWS * H_; e += THREADS)
    sh_hA[e >> 7][e & 127] = sx[blk * ROWS * H_ + e];
  __syncthreads();

#pragma unroll 1
  for (int t = 0; t < T_; ++t) {
    // ---- stage x_t (1024 elems) ----
    { int row = tid >> 6, d = tid & 63;
      sh_x[row][d] = x[(blk * ROWS + row) * (D_ * T_) + d * T_ + t]; }
    __syncthreads();

    // ---- gi: owner j computes 16 k-ascending chains ----
    if (isrow) {
      float acc[16];
#pragma unroll
      for (int rr = 0; rr < 16; ++rr) acc[rr] = bih_j;
#pragma unroll 2
      for (int kk = 0; kk < D_ / 4; ++kk) {
        float4 wv = *(const float4*)(wih2 + (kk * 384 + tid) * 4);
#pragma unroll
        for (int rr = 0; rr < 16; ++rr) {
          float4 hv = *(const float4*)&sh_x[rr][kk * 4];
          acc[rr] = fmaf(wv.x, hv.x, acc[rr]);
          acc[rr] = fmaf(wv.y, hv.y, acc[rr]);
          acc[rr] = fmaf(wv.z, hv.z, acc[rr]);
          acc[rr] = fmaf(wv.w, hv.w, acc[rr]);
        }
      }
#pragma unroll
      for (int rr = 0; rr < 16; ++rr) sh_gi[tid * 17 + rr] = acc[rr];
    }
    // (no barrier: P1 doesn't read gi; P1's trailing barrier orders gi->combine)

    float st0 = 0.0f, st1 = 0.0f, yt = 0.0f;
    float csum = 0.0f, pmprev = 0.0f, rt = 0.0f;
    int nt = -1;

#pragma unroll 1
    for (int m = 0; m < M_; ++m) {
      // ---- P1: gh chains, coalesced weights, 16-row reuse ----
      if (isrow) {
        float acc[16];
#pragma unroll
        for (int rr = 0; rr < 16; ++rr) acc[rr] = bhh_j;
#pragma unroll 2
        for (int kk = 0; kk < H_ / 4; ++kk) {
          float4 wv = *(const float4*)(whh2 + (kk * 384 + tid) * 4);
#pragma unroll
          for (int rr = 0; rr < 16; ++rr) {
            float4 hv = *(const float4*)&sh_hA[rr][kk * 4];
            acc[rr] = fmaf(wv.x, hv.x, acc[rr]);
            acc[rr] = fmaf(wv.y, hv.y, acc[rr]);
            acc[rr] = fmaf(wv.z, hv.z, acc[rr]);
            acc[rr] = fmaf(wv.w, hv.w, acc[rr]);
          }
        }
#pragma unroll
        for (int rr = 0; rr < 16; ++rr) sh_gh[tid * 17 + rr] = acc[rr];
      }
      __syncthreads();

      // ---- combine: 2048 (i,rr) tasks -> sh_hB ----
#pragma unroll
      for (int vv = 0; vv < 2; ++vv) {
        int v = tid + vv * THREADS;
        int rr = v & 15, i = v >> 4;
        float ghr = sh_gh[(0 * H_ + i) * 17 + rr];
        float ghz = sh_gh[(1 * H_ + i) * 17 + rr];
        float ghn = sh_gh[(2 * H_ + i) * 17 + rr];
        float gir = sh_gi[(0 * H_ + i) * 17 + rr];
        float giz = sh_gi[(1 * H_ + i) * 17 + rr];
        float gin = sh_gi[(2 * H_ + i) * 17 + rr];
        float rg = sigmoid_f(gir + ghr);
        float zg = sigmoid_f(giz + ghz);
        float ng = tanhf(fmaf(rg, ghn, gin));
        float hprev = sh_hA[rr][i];
        sh_hB[rr][i] = (1.0f - zg) * ng + zg * hprev;
      }
      __syncthreads();

      // ---- P2-dot: (We-row, row-quad) owners -> sh_enc ----
      if (tid < 256) {
        int wr = tid & 63, rq = tid >> 6;
        float acc[4];
#pragma unroll
        for (int qq = 0; qq < 4; ++qq) acc[qq] = be[wr];
#pragma unroll 4
        for (int kk = 0; kk < H_ / 4; ++kk) {
          float4 wv = *(const float4*)(we2 + (kk * 64 + wr) * 4);
#pragma unroll
          for (int qq = 0; qq < 4; ++qq) {
            float4 hv = *(const float4*)&sh_hB[rq * 4 + qq][kk * 4];
            acc[qq] = fmaf(wv.x, hv.x, acc[qq]);
            acc[qq] = fmaf(wv.y, hv.y, acc[qq]);
            acc[qq] = fmaf(wv.z, hv.z, acc[qq]);
            acc[qq] = fmaf(wv.w, hv.w, acc[qq]);
          }
        }
#pragma unroll
        for (int qq = 0; qq < 4; ++qq) sh_enc[wr * 17 + rq * 4 + qq] = acc[qq];
      }
      __syncthreads();

      // ---- zdraw: 512 threads, one (r,kd) each ----
      if (tid < 512) {
        int rz = tid & 15, kz = tid >> 4;          // kz 0..31
        float accM = sh_enc[kz * 17 + rz];
        float accS = sh_enc[(K_ + kz) * 17 + rz];
        float sg = softplus_f(accS - 5.0f);
        uint32_t key0 = sh_keys[t * M_ + m][0];
        uint32_t key1 = sh_keys[t * M_ + m][1];
        uint32_t e = (uint32_t)(blk * ROWS + rz) * 32u + (uint32_t)kz;
        uint32_t r0, r1;
        tf2x32(key0, key1, 0u, e, r0, r1);
        uint32_t bits = r0 ^ r1;
        float f = __uint_as_float((bits >> 9) | 0x3f800000u) - 1.0f;
        float u = fmaf(f, 2.0f, -0.99999994f);
        u = fmaxf(-0.99999994f, u);
        float eps = 1.41421356f * erfinv_f(u);
        sh_z[rz][kz] = fmaf(eps, sg, accM);
      }
      __syncthreads();

      // ---- P3: (Wl-row, row-half) owners -> sh_hA ----
      if (tid < 256) {
        int j = tid & 127, rh = tid >> 7;          // rh 0..1
        float acc[8];
#pragma unroll
        for (int rr2 = 0; rr2 < 8; ++rr2) acc[rr2] = bl[j];
#pragma unroll
        for (int kk = 0; kk < K_ / 4; ++kk) {
          float4 wv = *(const float4*)(wl2 + (kk * 128 + j) * 4);
#pragma unroll
          for (int rr2 = 0; rr2 < 8; ++rr2) {
            float4 zv = *(const float4*)&sh_z[rh * 8 + rr2][kk * 4];
            acc[rr2] = fmaf(wv.x, zv.x, acc[rr2]);
            acc[rr2] = fmaf(wv.y, zv.y, acc[rr2]);
            acc[rr2] = fmaf(wv.z, zv.z, acc[rr2]);
            acc[rr2] = fmaf(wv.w, zv.w, acc[rr2]);
          }
        }
#pragma unroll
        for (int rr2 = 0; rr2 < 8; ++rr2)
          sh_hA[rh * 8 + rr2][j] = tanhf(acc[rr2]);
      }
      __syncthreads();

      // ---- P4: pn (full chain, all threads), y quarter + shuffle tree ----
      {
        float pa = bhalt[0];
#pragma unroll 2
        for (int kk = 0; kk < H_ / 4; ++kk) {
          float4 hv = *(const float4*)&sh_hA[r16][kk * 4];
          float4 av = *(const float4*)(Whalt + kk * 4);   // wave-uniform -> s_load
          pa = fmaf(av.x, hv.x, pa); pa = fmaf(av.y, hv.y, pa);
          pa = fmaf(av.z, hv.z, pa); pa = fmaf(av.w, hv.w, pa);
        }
        float pn = sigmoid_f(pa);

        float yv = 0.0f;
        if (c < NC_) {
          float yq = (q == 0) ? bo[c] : 0.0f;
          const float* wo = Wo + c * H_ + q * 32;
#pragma unroll
          for (int kk = 0; kk < 8; ++kk) {
            float4 hv = *(const float4*)&sh_hA[r16][q * 32 + kk * 4];
            float4 ov = *(const float4*)(wo + kk * 4);
            yq = fmaf(ov.x, hv.x, yq); yq = fmaf(ov.y, hv.y, yq);
            yq = fmaf(ov.z, hv.z, yq); yq = fmaf(ov.w, hv.w, yq);
          }
          yq += __shfl_xor(yq, 16);   // combine q^1
          yq += __shfl_xor(yq, 32);   // combine q^2
          yv = yq;
        }

        csum += pn;
        float pm = (m == M_ - 1) ? 1.0f : fminf(1.0f, csum);
        if (nt < 0 && (csum >= 1.0f || m == M_ - 1)) {
          nt = m;
          rt = (m == 0) ? 0.0f : (1.0f - pmprev);
        }
        float ph = pm - pmprev;
        pmprev = pm;
        st0 = fmaf(ph, sh_hA[r16][i0], st0);
        st1 = fmaf(ph, sh_hA[r16][i0 + 1], st1);
        yt = fmaf(ph, yv, yt);
      }
      // no barrier: next P1 only reads hA and writes gh (last read 4 bars ago)
    }  // ticks

    // ---- step end ----
    __syncthreads();   // all P4 hA reads done
    sh_hA[r16][i0] = st0;
    sh_hA[r16][i0 + 1] = st1;
    if (c < NC_ && q == 0) out[b * (NC_ * T_) + c * T_ + t] = yt;
    if (idx == 40) {
      out[P_OFF + b * T_ + t] = (float)nt + rt;
      out[N_OFF + b * T_ + t] = (float)nt;
    }
    if (t == T_ - 1) {
      out[SX_OFF + b * H_ + i0] = st0;
      out[SX_OFF + b * H_ + i0 + 1] = st1;
    }
    __syncthreads();
  }  // steps
}

extern "C" void kernel_launch(void* const* d_in, const int* in_sizes, int n_in,
                              void* d_out, int out_size, void* d_ws, size_t ws_size,
                              hipStream_t stream) {
  (void)in_sizes; (void)n_in; (void)out_size; (void)ws_size;
  const float* x     = (const float*)d_in[0];
  const float* sx    = (const float*)d_in[1];
  const float* Wih   = (const float*)d_in[2];
  const float* Whh   = (const float*)d_in[3];
  const float* bih   = (const float*)d_in[4];
  const float* bhh   = (const float*)d_in[5];
  const float* We    = (const float*)d_in[6];
  const float* be    = (const float*)d_in[7];
  const float* Wl    = (const float*)d_in[8];
  const float* bl    = (const float*)d_in[9];
  const float* Wo    = (const float*)d_in[10];
  const float* bo    = (const float*)d_in[11];
  const float* Whalt = (const float*)d_in[12];
  const float* bhalt = (const float*)d_in[13];
  float* ws  = (float*)d_ws;
  float* out = (float*)d_out;

  reorder_kernel<<<dim3((WS_TOT + 255) / 256), dim3(256), 0, stream>>>(Whh, Wih, We, Wl, ws);
  vrnn_kernel<<<dim3(B_ / ROWS), dim3(THREADS), 0, stream>>>(x, sx, bih, bhh, be, bl,
                                                             Wo, bo, Whalt, bhalt, ws, out);
}

// Round 11
// 2201.196 us; speedup vs baseline: 7.3253x; 2.9032x over previous
//
#include <hip/hip_runtime.h>
#include <hip/hip_bf16.h>
#include <stdint.h>

#define B_ 4096
#define D_ 64
#define T_ 8
#define H_ 128
#define K_ 32
#define NC_ 10
#define M_ 14

#define P_OFF (B_*NC_*T_)            /* 327680 */
#define N_OFF (P_OFF + B_*T_)        /* 360448 */
#define SX_OFF (N_OFF + B_*T_)       /* 393216 */

#define ROWS 8       /* batch rows per block */
#define THREADS 512

/* ws float offsets for transposed weights: W2[kk][row][4] layouts */
#define WS_WHH 0        /* 32 kk x 384 rows x4 = 49152 */
#define WS_WIH 49152    /* 16 kk x 384 x4 = 24576 */
#define WS_WE  73728    /* 32 kk x 64 x4  = 8192 */
#define WS_WL  81920    /* 8 kk x 128 x4  = 4096 */
#define WS_TOT 86016    /* 344 KB */

// ---------------- Threefry-2x32 (20 rounds), exactly JAX's ----------------
__device__ __forceinline__ void tf2x32(uint32_t k0, uint32_t k1,
                                       uint32_t c0, uint32_t c1,
                                       uint32_t& o0, uint32_t& o1) {
  uint32_t ks2 = k0 ^ k1 ^ 0x1BD11BDAu;
  uint32_t x0 = c0 + k0, x1 = c1 + k1;
#define TF_R(r) { x0 += x1; x1 = ((x1 << (r)) | (x1 >> (32 - (r)))); x1 ^= x0; }
  TF_R(13) TF_R(15) TF_R(26) TF_R(6)
  x0 += k1; x1 += ks2 + 1u;
  TF_R(17) TF_R(29) TF_R(16) TF_R(24)
  x0 += ks2; x1 += k0 + 2u;
  TF_R(13) TF_R(15) TF_R(26) TF_R(6)
  x0 += k0; x1 += k1 + 3u;
  TF_R(17) TF_R(29) TF_R(16) TF_R(24)
  x0 += k1; x1 += ks2 + 4u;
  TF_R(13) TF_R(15) TF_R(26) TF_R(6)
  x0 += ks2; x1 += k0 + 5u;
#undef TF_R
  o0 = x0; o1 = x1;
}

// XLA ErfInv32 (Giles single-precision polynomial)
__device__ __forceinline__ float erfinv_f(float x) {
  float w = -log1pf(-x * x);
  float p;
  if (w < 5.0f) {
    w -= 2.5f;
    p = 2.81022636e-08f;
    p = fmaf(p, w, 3.43273939e-07f);
    p = fmaf(p, w, -3.5233877e-06f);
    p = fmaf(p, w, -4.39150654e-06f);
    p = fmaf(p, w, 0.00021858087f);
    p = fmaf(p, w, -0.00125372503f);
    p = fmaf(p, w, -0.00417768164f);
    p = fmaf(p, w, 0.246640727f);
    p = fmaf(p, w, 1.50140941f);
  } else {
    w = sqrtf(w) - 3.0f;
    p = -0.000200214257f;
    p = fmaf(p, w, 0.000100950558f);
    p = fmaf(p, w, 0.00134934322f);
    p = fmaf(p, w, -0.00367342844f);
    p = fmaf(p, w, 0.00573950773f);
    p = fmaf(p, w, -0.0076224613f);
    p = fmaf(p, w, 0.00943887047f);
    p = fmaf(p, w, 1.00167406f);
    p = fmaf(p, w, 2.83297682f);
  }
  return p * x;
}

__device__ __forceinline__ float sigmoid_f(float x) { return 1.0f / (1.0f + expf(-x)); }
__device__ __forceinline__ float softplus_f(float x) {
  return (x > 0.0f) ? (x + log1pf(expf(-x))) : log1pf(expf(x));
}

// ---- prologue: transpose weights into ws as W2[kk][row][4] (coalesced reads) ----
__launch_bounds__(256)
__global__ void reorder_kernel(const float* __restrict__ Whh, const float* __restrict__ Wih,
                               const float* __restrict__ We, const float* __restrict__ Wl,
                               float* __restrict__ ws) {
  int i = (int)blockIdx.x * 256 + (int)threadIdx.x;
  if (i < 49152) {                       // Whh: 384x128
    int e = i & 3, ch = i >> 2, j = ch % 384, kk = ch / 384;
    ws[WS_WHH + i] = Whh[j * H_ + kk * 4 + e];
  } else if (i < 73728) {                // Wih: 384x64
    int x2 = i - WS_WIH;
    int e = x2 & 3, ch = x2 >> 2, j = ch % 384, kk = ch / 384;
    ws[i] = Wih[j * D_ + kk * 4 + e];
  } else if (i < 81920) {                // We: 64x128
    int x2 = i - WS_WE;
    int e = x2 & 3, ch = x2 >> 2, j = ch % 64, kk = ch / 64;
    ws[i] = We[j * H_ + kk * 4 + e];
  } else if (i < WS_TOT) {               // Wl: 128x32
    int x2 = i - WS_WL;
    int e = x2 & 3, ch = x2 >> 2, j = ch % 128, kk = ch / 128;
    ws[i] = Wl[j * K_ + kk * 4 + e];
  }
}

// 512 blocks x 512 threads, 8 batch rows/block (2 blocks/CU).
// P1/gi: threads 0..383 own matrix row j=tid; coalesced W2 float4 loads,
//        8-row reuse via wave-uniform LDS-broadcast h reads; acc[8] only.
// combine: 1024 (i,rr) tasks / 512 threads, exact GRU algebra.
// P2: 512 tasks (We-row 0..63 x batch-row 0..7), coalesced; z-draw inline
//     on mu threads via __shfl_xor(acc,32).
// P3: (Wl-row 0..127) x (row-pair 0..3), acc[2], coalesced.
// P4: round-6 logic verbatim (r=tid&7, idx=tid>>3).
__launch_bounds__(THREADS, 2)
__global__ void vrnn_kernel(const float* __restrict__ x, const float* __restrict__ sx,
                            const float* __restrict__ bih, const float* __restrict__ bhh,
                            const float* __restrict__ be, const float* __restrict__ bl,
                            const float* __restrict__ Wo, const float* __restrict__ bo,
                            const float* __restrict__ Whalt, const float* __restrict__ bhalt,
                            const float* __restrict__ ws, float* __restrict__ out) {
  __shared__ float sh_hA[ROWS][132];     // h carry / hb
  __shared__ float sh_hB[ROWS][132];     // h_gru
  __shared__ float sh_gh[384 * 9];       // 13.8 KB
  __shared__ float sh_gi[384 * 9];       // 13.8 KB
  __shared__ float sh_z[ROWS][36];
  __shared__ float sh_x[ROWS][68];
  __shared__ uint32_t sh_keys[T_ * M_][2];

  const int tid = (int)threadIdx.x;
  const int r = tid & 7;
  const int idx = tid >> 3;              // 0..63
  const int i0 = idx * 2;
  const int c = idx >> 2;                // y dot (0..15)
  const int q = idx & 3;                 // y quarter
  const int blk = (int)blockIdx.x;
  const int b = blk * ROWS + r;
  const bool isrow = (tid < 384);

  const float* whh2 = ws + WS_WHH;
  const float* wih2 = ws + WS_WIH;
  const float* we2  = ws + WS_WE;
  const float* wl2  = ws + WS_WL;

  if (tid < T_ * M_) {
    uint32_t o0, o1;
    tf2x32(0u, 42u, 0u, (uint32_t)tid, o0, o1);
    sh_keys[tid][0] = o0;
    sh_keys[tid][1] = o1;
  }

  float bhh_j = 0.0f, bih_j = 0.0f;
  if (isrow) { bhh_j = bhh[tid]; bih_j = bih[tid]; }

  // init h carry = sx
#pragma unroll
  for (int e = tid; e < ROWS * H_; e += THREADS)
    sh_hA[e >> 7][e & 127] = sx[blk * ROWS * H_ + e];
  __syncthreads();

#pragma unroll 1
  for (int t = 0; t < T_; ++t) {
    // ---- stage x_t (512 elems) ----
    { int row = tid >> 6, d = tid & 63;
      sh_x[row][d] = x[(blk * ROWS + row) * (D_ * T_) + d * T_ + t]; }
    __syncthreads();

    // ---- gi: owner j, 8 k-ascending chains, coalesced Wih ----
    if (isrow) {
      float acc[8];
#pragma unroll
      for (int rr = 0; rr < 8; ++rr) acc[rr] = bih_j;
#pragma unroll 2
      for (int kk = 0; kk < D_ / 4; ++kk) {
        float4 wv = *(const float4*)(wih2 + (kk * 384 + tid) * 4);
#pragma unroll
        for (int rr = 0; rr < 8; ++rr) {
          float4 hv = *(const float4*)&sh_x[rr][kk * 4];
          acc[rr] = fmaf(wv.x, hv.x, acc[rr]);
          acc[rr] = fmaf(wv.y, hv.y, acc[rr]);
          acc[rr] = fmaf(wv.z, hv.z, acc[rr]);
          acc[rr] = fmaf(wv.w, hv.w, acc[rr]);
        }
      }
#pragma unroll
      for (int rr = 0; rr < 8; ++rr) sh_gi[tid * 9 + rr] = acc[rr];
    }
    // no barrier: P1's trailing barrier orders gi -> combine

    float st0 = 0.0f, st1 = 0.0f, yt = 0.0f;
    float csum = 0.0f, pmprev = 0.0f, rt = 0.0f;
    int nt = -1;

#pragma unroll 1
    for (int m = 0; m < M_; ++m) {
      // ---- P1: gh chains, coalesced weights, 8-row reuse ----
      if (isrow) {
        float acc[8];
#pragma unroll
        for (int rr = 0; rr < 8; ++rr) acc[rr] = bhh_j;
#pragma unroll 2
        for (int kk = 0; kk < H_ / 4; ++kk) {
          float4 wv = *(const float4*)(whh2 + (kk * 384 + tid) * 4);
#pragma unroll
          for (int rr = 0; rr < 8; ++rr) {
            float4 hv = *(const float4*)&sh_hA[rr][kk * 4];
            acc[rr] = fmaf(wv.x, hv.x, acc[rr]);
            acc[rr] = fmaf(wv.y, hv.y, acc[rr]);
            acc[rr] = fmaf(wv.z, hv.z, acc[rr]);
            acc[rr] = fmaf(wv.w, hv.w, acc[rr]);
          }
        }
#pragma unroll
        for (int rr = 0; rr < 8; ++rr) sh_gh[tid * 9 + rr] = acc[rr];
      }
      __syncthreads();

      // ---- combine: 1024 (i,rr) tasks -> sh_hB ----
#pragma unroll
      for (int vv = 0; vv < 2; ++vv) {
        int v = tid + vv * THREADS;
        int rr = v & 7, i = v >> 3;
        float ghr = sh_gh[(0 * H_ + i) * 9 + rr];
        float ghz = sh_gh[(1 * H_ + i) * 9 + rr];
        float ghn = sh_gh[(2 * H_ + i) * 9 + rr];
        float gir = sh_gi[(0 * H_ + i) * 9 + rr];
        float giz = sh_gi[(1 * H_ + i) * 9 + rr];
        float gin = sh_gi[(2 * H_ + i) * 9 + rr];
        float rg = sigmoid_f(gir + ghr);
        float zg = sigmoid_f(giz + ghz);
        float ng = tanhf(fmaf(rg, ghn, gin));
        float hprev = sh_hA[rr][i];
        sh_hB[rr][i] = (1.0f - zg) * ng + zg * hprev;
      }
      __syncthreads();

      // ---- P2: (We-row wr, batch-row rr2) coalesced dot + inline z-draw ----
      {
        int wr = tid & 63, rr2 = tid >> 6;   // 512 tasks exactly
        float acc = be[wr];
#pragma unroll 4
        for (int kk = 0; kk < H_ / 4; ++kk) {
          float4 wv = *(const float4*)(we2 + (kk * 64 + wr) * 4);
          float4 hv = *(const float4*)&sh_hB[rr2][kk * 4];
          acc = fmaf(wv.x, hv.x, acc);
          acc = fmaf(wv.y, hv.y, acc);
          acc = fmaf(wv.z, hv.z, acc);
          acc = fmaf(wv.w, hv.w, acc);
        }
        float accP = __shfl_xor(acc, 32);    // partner wr^32, same rr2
        if (wr < K_) {                       // mu thread: kd=wr, row rr2
          float sg = softplus_f(accP - 5.0f);
          uint32_t key0 = sh_keys[t * M_ + m][0];
          uint32_t key1 = sh_keys[t * M_ + m][1];
          uint32_t e = (uint32_t)(blk * ROWS + rr2) * 32u + (uint32_t)wr;
          uint32_t r0, r1;
          tf2x32(key0, key1, 0u, e, r0, r1);
          uint32_t bits = r0 ^ r1;
          float f = __uint_as_float((bits >> 9) | 0x3f800000u) - 1.0f;
          float u = fmaf(f, 2.0f, -0.99999994f);
          u = fmaxf(-0.99999994f, u);
          float eps = 1.41421356f * erfinv_f(u);
          sh_z[rr2][wr] = fmaf(eps, sg, acc);
        }
      }
      __syncthreads();

      // ---- P3: (Wl-row jl, row-pair rh) coalesced, acc[2] -> sh_hA ----
      {
        int jl = tid & 127, rh = tid >> 7;   // rh 0..3 -> rows 2rh, 2rh+1
        float a0 = bl[jl], a1 = a0;
#pragma unroll
        for (int kk = 0; kk < K_ / 4; ++kk) {
          float4 wv = *(const float4*)(wl2 + (kk * 128 + jl) * 4);
          float4 z0 = *(const float4*)&sh_z[rh * 2][kk * 4];
          float4 z1 = *(const float4*)&sh_z[rh * 2 + 1][kk * 4];
          a0 = fmaf(wv.x, z0.x, a0); a1 = fmaf(wv.x, z1.x, a1);
          a0 = fmaf(wv.y, z0.y, a0); a1 = fmaf(wv.y, z1.y, a1);
          a0 = fmaf(wv.z, z0.z, a0); a1 = fmaf(wv.z, z1.z, a1);
          a0 = fmaf(wv.w, z0.w, a0); a1 = fmaf(wv.w, z1.w, a1);
        }
        sh_hA[rh * 2][jl] = tanhf(a0);
        sh_hA[rh * 2 + 1][jl] = tanhf(a1);
      }
      __syncthreads();

      // ---- P4: pn (full chain), y quarter + shuffle tree, halting ----
      {
        float pa = bhalt[0];
#pragma unroll 2
        for (int kk = 0; kk < H_ / 4; ++kk) {
          float4 hv = *(const float4*)&sh_hA[r][kk * 4];
          float4 av = *(const float4*)(Whalt + kk * 4);   // uniform -> s_load
          pa = fmaf(av.x, hv.x, pa); pa = fmaf(av.y, hv.y, pa);
          pa = fmaf(av.z, hv.z, pa); pa = fmaf(av.w, hv.w, pa);
        }
        float pn = sigmoid_f(pa);

        float yv = 0.0f;
        if (c < NC_) {
          float yq = (q == 0) ? bo[c] : 0.0f;
          const float* wo = Wo + c * H_ + q * 32;
#pragma unroll
          for (int kk = 0; kk < 8; ++kk) {
            float4 hv = *(const float4*)&sh_hA[r][q * 32 + kk * 4];
            float4 ov = *(const float4*)(wo + kk * 4);
            yq = fmaf(ov.x, hv.x, yq); yq = fmaf(ov.y, hv.y, yq);
            yq = fmaf(ov.z, hv.z, yq); yq = fmaf(ov.w, hv.w, yq);
          }
          yq += __shfl_xor(yq, 8);
          yq += __shfl_xor(yq, 16);
          yv = yq;
        }

        csum += pn;
        float pm = (m == M_ - 1) ? 1.0f : fminf(1.0f, csum);
        if (nt < 0 && (csum >= 1.0f || m == M_ - 1)) {
          nt = m;
          rt = (m == 0) ? 0.0f : (1.0f - pmprev);
        }
        float ph = pm - pmprev;
        pmprev = pm;
        st0 = fmaf(ph, sh_hA[r][i0], st0);
        st1 = fmaf(ph, sh_hA[r][i0 + 1], st1);
        yt = fmaf(ph, yv, yt);
      }
      // no barrier: next P1 reads hA (stable since P3 bar) and writes gh
      // (last read at combine, 3 bars earlier)
    }  // ticks

    // ---- step end ----
    __syncthreads();   // all P4 hA reads done
    sh_hA[r][i0] = st0;
    sh_hA[r][i0 + 1] = st1;
    if (c < NC_ && q == 0) out[b * (NC_ * T_) + c * T_ + t] = yt;
    if (idx == 40) {
      out[P_OFF + b * T_ + t] = (float)nt + rt;
      out[N_OFF + b * T_ + t] = (float)nt;
    }
    if (t == T_ - 1) {
      out[SX_OFF + b * H_ + i0] = st0;
      out[SX_OFF + b * H_ + i0 + 1] = st1;
    }
    __syncthreads();
  }  // steps
}

extern "C" void kernel_launch(void* const* d_in, const int* in_sizes, int n_in,
                              void* d_out, int out_size, void* d_ws, size_t ws_size,
                              hipStream_t stream) {
  (void)in_sizes; (void)n_in; (void)out_size; (void)ws_size;
  const float* x     = (const float*)d_in[0];
  const float* sx    = (const float*)d_in[1];
  const float* Wih   = (const float*)d_in[2];
  const float* Whh   = (const float*)d_in[3];
  const float* bih   = (const float*)d_in[4];
  const float* bhh   = (const float*)d_in[5];
  const float* We    = (const float*)d_in[6];
  const float* be    = (const float*)d_in[7];
  const float* Wl    = (const float*)d_in[8];
  const float* bl    = (const float*)d_in[9];
  const float* Wo    = (const float*)d_in[10];
  const float* bo    = (const float*)d_in[11];
  const float* Whalt = (const float*)d_in[12];
  const float* bhalt = (const float*)d_in[13];
  float* ws  = (float*)d_ws;
  float* out = (float*)d_out;

  reorder_kernel<<<dim3((WS_TOT + 255) / 256), dim3(256), 0, stream>>>(Whh, Wih, We, Wl, ws);
  vrnn_kernel<<<dim3(B_ / ROWS), dim3(THREADS), 0, stream>>>(x, sx, bih, bhh, be, bl,
                                                             Wo, bo, Whalt, bhalt, ws, out);
}